// Round 4
// baseline (19168.648 us; speedup 1.0000x reference)
//
#include <hip/hip_runtime.h>
#include <hip/hip_bf16.h>

#define B_ 32
#define S_ 64
#define V_ 96
#define E_ 256
#define H_ 512
#define L_ 3
#define DIN_ 1024
#define G4_ 2048
#define BH_ (B_*H_)

typedef unsigned short u16;

__device__ __forceinline__ float bfu(u16 u){ return __uint_as_float(((unsigned)u) << 16); }
__device__ __forceinline__ u16 f2b(float f){           // RNE float->bf16
  unsigned x = __float_as_uint(f);
  unsigned r = (x + 0x7FFFu + ((x >> 16) & 1u)) >> 16;
  return (u16)r;
}
__device__ __forceinline__ float sigm(float x){ return 1.f/(1.f+__expf(-x)); }
__device__ __forceinline__ float wred(float a){
  #pragma unroll
  for(int off=32; off; off>>=1) a += __shfl_down(a, off);
  return a;
}
// Dual-dtype INPUT loads. BF=1: buffer is bf16 (u16); BF=0: buffer is fp32.
template<int BF> __device__ __forceinline__ float LD(const void* p, size_t i){
  if constexpr(BF) return bfu(((const u16*)p)[i]);
  else             return ((const float*)p)[i];
}
template<int BF> __device__ __forceinline__ float4 LD4(const void* p, size_t i){
  if constexpr(BF){
    const u16* q = (const u16*)p + i;
    ushort4 w = *(const ushort4*)q;
    return make_float4(bfu(w.x), bfu(w.y), bfu(w.z), bfu(w.w));
  } else {
    return *(const float4*)((const float*)p + i);
  }
}

// ---------------------------------------------------------------------------
// Dtype probe: attn_v = uniform(0,1), 512 elements. bf16 => even u16 indices
// are positive bf16s (bit15=0). fp32 => even u16s are random mantissa halves
// (~50% bit15 set). Reads 1KB, safe under both interpretations.
__global__ void k_detect(const void* av, int* flag){
  __shared__ int cnt;
  if(threadIdx.x == 0) cnt = 0;
  __syncthreads();
  u16 w = ((const u16*)av)[2*threadIdx.x];
  if(w & 0x8000) atomicAdd(&cnt, 1);
  __syncthreads();
  if(threadIdx.x == 0) *flag = (cnt <= 8) ? 1 : 0;   // 1 = bf16 inputs
}

// ---------------------------------------------------------------------------
__global__ void k_zero(float* __restrict__ p, int n){
  int i = blockIdx.x*256 + threadIdx.x;
  if(i < n) p[i] = 0.f;
}

// ---------------------------------------------------------------------------
// X0[(s*B+b)*DIN + d] = emb[src[b,s], d] (d<E), else 0.  X is fp32 in ws.
template<int BF> __device__ void embed_body(const int* __restrict__ src,
                                            const void* __restrict__ emb,
                                            float* __restrict__ X0){
  int idx = blockIdx.x*256 + threadIdx.x;   // exactly S*B*DIN threads
  int d  = idx & (DIN_-1);
  int sb = idx >> 10;
  int b  = sb & (B_-1);
  int s  = sb >> 5;
  float v = 0.f;
  if(d < E_){
    int tok = src[b*S_ + s];
    v = LD<BF>(emb, (size_t)tok*E_ + d);
  }
  X0[idx] = v;
}
__global__ void k_embed(const int* src, const void* emb, float* X0, const int* fl){
  if(*fl) embed_body<1>(src, emb, X0); else embed_body<0>(src, emb, X0);
}

// ---------------------------------------------------------------------------
// Tiled GEMM: C[m,n] = sum_k A[m*lda+k] * W[woff + n*ldw + k] + b1[n] + b2[n]
// A fp32 (ws); W/b1/b2 input dtype per BF. C fp32.
// Tile 128(m) x 64(n), 256 threads, 8x4 per thread, K multiple of 16.
template<int BF> __device__ void gemm_body(
  const float* __restrict__ A, int lda,
  const void* __restrict__ W, int ldw, size_t woff,
  const void* __restrict__ b1, size_t o1,
  const void* __restrict__ b2, size_t o2,
  float* __restrict__ C, int ldc, int K)
{
  __shared__ float As[16][128];
  __shared__ float Bs[16][64];
  const int tid = threadIdx.x;
  const int m0 = blockIdx.y * 128;
  const int n0 = blockIdx.x * 64;
  const int tx = tid & 15, ty = tid >> 4;
  const int amm = tid & 127, akk = (tid >> 7) * 8;
  const int bnn = tid >> 2,  bkk = (tid & 3) * 4;
  float acc[8][4] = {{0.f}};
  for(int k0 = 0; k0 < K; k0 += 16){
    const float4* ap = (const float4*)(A + (size_t)(m0+amm)*lda + (k0 + akk));
    float4 a0 = ap[0];
    float4 a1 = ap[1];
    float4 wv = LD4<BF>(W, woff + (size_t)(n0+bnn)*ldw + (k0 + bkk));
    As[akk+0][amm]=a0.x; As[akk+1][amm]=a0.y; As[akk+2][amm]=a0.z; As[akk+3][amm]=a0.w;
    As[akk+4][amm]=a1.x; As[akk+5][amm]=a1.y; As[akk+6][amm]=a1.z; As[akk+7][amm]=a1.w;
    Bs[bkk+0][bnn]=wv.x; Bs[bkk+1][bnn]=wv.y;
    Bs[bkk+2][bnn]=wv.z; Bs[bkk+3][bnn]=wv.w;
    __syncthreads();
    #pragma unroll
    for(int kk=0;kk<16;kk++){
      const float4 av0 = *(const float4*)&As[kk][ty*8];
      const float4 av1 = *(const float4*)&As[kk][ty*8+4];
      const float4 bv  = *(const float4*)&Bs[kk][tx*4];
      float am[8] = {av0.x,av0.y,av0.z,av0.w,av1.x,av1.y,av1.z,av1.w};
      float bn[4] = {bv.x,bv.y,bv.z,bv.w};
      #pragma unroll
      for(int i=0;i<8;i++){
        #pragma unroll
        for(int j=0;j<4;j++) acc[i][j] = fmaf(am[i], bn[j], acc[i][j]);
      }
    }
    __syncthreads();
  }
  float bias[4];
  #pragma unroll
  for(int j=0;j<4;j++){
    float bb = 0.f;
    if(b1) bb += LD<BF>(b1, o1 + n0 + tx*4 + j);
    if(b2) bb += LD<BF>(b2, o2 + n0 + tx*4 + j);
    bias[j] = bb;
  }
  #pragma unroll
  for(int i=0;i<8;i++){
    float* cp = C + (size_t)(m0 + ty*8 + i)*ldc + (n0 + tx*4);
    #pragma unroll
    for(int j=0;j<4;j++) cp[j] = acc[i][j] + bias[j];
  }
}
__global__ __launch_bounds__(256) void k_gemm(
  const float* A, int lda, const void* W, int ldw, size_t woff,
  const void* b1, size_t o1, const void* b2, size_t o2,
  float* C, int ldc, int K, const int* fl)
{
  if(*fl) gemm_body<1>(A,lda,W,ldw,woff,b1,o1,b2,o2,C,ldc,K);
  else    gemm_body<0>(A,lda,W,ldw,woff,b1,o1,b2,o2,C,ldc,K);
}

// ---------------------------------------------------------------------------
// Plan A encoder cell step p: both dirs. Wave per (dir,b,j). Gate = G + h@Whh.T.
// G layout: [(t*B+b), dir*2048 + gate*512 + j] fp32, gates i,f,g,o.
template<int BF> __device__ void enc_cell_body(
  const float* __restrict__ G, const void* __restrict__ Whh, size_t oW,
  const float* __restrict__ hf_in, const float* __restrict__ cf_in,
  float* __restrict__ hf_out, float* __restrict__ cf_out,
  const float* __restrict__ hb_in, const float* __restrict__ cb_in,
  float* __restrict__ hb_out, float* __restrict__ cb_out,
  float* __restrict__ Xn, int p)
{
  int wave = blockIdx.x*4 + (threadIdx.x>>6);
  int lane = threadIdx.x & 63;
  int j = wave & (H_-1);
  int b = (wave >> 9) & (B_-1);
  int d = wave >> 14;
  const float* h_in = d ? hb_in : hf_in;
  const float* c_in = d ? cb_in : cf_in;
  float* h_out = d ? hb_out : hf_out;
  float* c_out = d ? cb_out : cf_out;
  size_t wb = oW + (size_t)d*G4_*H_ + (size_t)j*H_;
  const float* hrow = h_in + b*H_;
  float a0=0.f,a1=0.f,a2=0.f,a3=0.f;
  #pragma unroll
  for(int i=0;i<8;i++){
    int k = lane + i*64;
    float hv = hrow[k];
    a0 = fmaf(hv, LD<BF>(Whh, wb + k), a0);
    a1 = fmaf(hv, LD<BF>(Whh, wb + (size_t)H_*H_ + k), a1);
    a2 = fmaf(hv, LD<BF>(Whh, wb + (size_t)2*H_*H_ + k), a2);
    a3 = fmaf(hv, LD<BF>(Whh, wb + (size_t)3*H_*H_ + k), a3);
  }
  a0 = wred(a0); a1 = wred(a1); a2 = wred(a2); a3 = wred(a3);
  if(lane == 0){
    int t = d ? (S_-1-p) : p;
    const float* Gr = G + (size_t)(t*B_ + b)*4096 + d*G4_ + j;
    float gi = Gr[0]     + a0;
    float gf = Gr[H_]    + a1;
    float gg = Gr[2*H_]  + a2;
    float go = Gr[3*H_]  + a3;
    float c2 = sigm(gf)*c_in[b*H_+j] + sigm(gi)*tanhf(gg);
    float h2 = sigm(go)*tanhf(c2);
    h_out[b*H_+j] = h2;
    c_out[b*H_+j] = c2;
    Xn[(size_t)(t*B_ + b)*DIN_ + d*H_ + j] = h2;
  }
}
__global__ __launch_bounds__(256) void k_enc_cell(
  const float* G, const void* Whh, size_t oW,
  const float* hfi, const float* cfi, float* hfo, float* cfo,
  const float* hbi, const float* cbi, float* hbo, float* cbo,
  float* Xn, int p, const int* fl)
{
  if(*fl) enc_cell_body<1>(G,Whh,oW,hfi,cfi,hfo,cfo,hbi,cbi,hbo,cbo,Xn,p);
  else    enc_cell_body<0>(G,Whh,oW,hfi,cfi,hfo,cfo,hbi,cbi,hbo,cbo,Xn,p);
}

// ---------------------------------------------------------------------------
// Plan B fused encoder cell (no G buffer): gates computed on the fly.
template<int BF> __device__ void enc_cellf_body(
  const float* __restrict__ Xin,
  const void* __restrict__ Wih, size_t oWi,
  const void* __restrict__ Whh, size_t oWh,
  const void* __restrict__ bih, size_t obi,
  const void* __restrict__ bhh, size_t obh,
  const float* __restrict__ hf_in, const float* __restrict__ cf_in,
  float* __restrict__ hf_out, float* __restrict__ cf_out,
  const float* __restrict__ hb_in, const float* __restrict__ cb_in,
  float* __restrict__ hb_out, float* __restrict__ cb_out,
  float* __restrict__ Xn, int p, int Kx)
{
  int wave = blockIdx.x*4 + (threadIdx.x>>6);
  int lane = threadIdx.x & 63;
  int j = wave & (H_-1);
  int b = (wave >> 9) & (B_-1);
  int d = wave >> 14;
  const float* h_in = d ? hb_in : hf_in;
  const float* c_in = d ? cb_in : cf_in;
  float* h_out = d ? hb_out : hf_out;
  float* c_out = d ? cb_out : cf_out;
  int t = d ? (S_-1-p) : p;
  const float* xr = Xin + (size_t)(t*B_ + b)*DIN_;
  size_t wi = oWi + ((size_t)d*G4_ + j)*DIN_;
  float a0=0.f,a1=0.f,a2=0.f,a3=0.f;
  for(int k=lane; k<Kx; k+=64){
    float xv = xr[k];
    a0 = fmaf(xv, LD<BF>(Wih, wi + k), a0);
    a1 = fmaf(xv, LD<BF>(Wih, wi + (size_t)H_*DIN_ + k), a1);
    a2 = fmaf(xv, LD<BF>(Wih, wi + (size_t)2*H_*DIN_ + k), a2);
    a3 = fmaf(xv, LD<BF>(Wih, wi + (size_t)3*H_*DIN_ + k), a3);
  }
  size_t wh = oWh + ((size_t)d*G4_ + j)*H_;
  const float* hrow = h_in + b*H_;
  #pragma unroll
  for(int i=0;i<8;i++){
    int k = lane + i*64;
    float hv = hrow[k];
    a0 = fmaf(hv, LD<BF>(Whh, wh + k), a0);
    a1 = fmaf(hv, LD<BF>(Whh, wh + (size_t)H_*H_ + k), a1);
    a2 = fmaf(hv, LD<BF>(Whh, wh + (size_t)2*H_*H_ + k), a2);
    a3 = fmaf(hv, LD<BF>(Whh, wh + (size_t)3*H_*H_ + k), a3);
  }
  a0 = wred(a0); a1 = wred(a1); a2 = wred(a2); a3 = wred(a3);
  if(lane == 0){
    size_t bb = (size_t)d*G4_ + j;
    float gi = a0 + LD<BF>(bih, obi+bb)        + LD<BF>(bhh, obh+bb);
    float gf = a1 + LD<BF>(bih, obi+bb+H_)     + LD<BF>(bhh, obh+bb+H_);
    float gg = a2 + LD<BF>(bih, obi+bb+2*H_)   + LD<BF>(bhh, obh+bb+2*H_);
    float go = a3 + LD<BF>(bih, obi+bb+3*H_)   + LD<BF>(bhh, obh+bb+3*H_);
    float c2 = sigm(gf)*c_in[b*H_+j] + sigm(gi)*tanhf(gg);
    float h2 = sigm(go)*tanhf(c2);
    h_out[b*H_+j] = h2;
    c_out[b*H_+j] = c2;
    Xn[(size_t)(t*B_ + b)*DIN_ + d*H_ + j] = h2;
  }
}
__global__ __launch_bounds__(256) void k_enc_cell_f(
  const float* Xin, const void* Wih, size_t oWi, const void* Whh, size_t oWh,
  const void* bih, size_t obi, const void* bhh, size_t obh,
  const float* hfi, const float* cfi, float* hfo, float* cfo,
  const float* hbi, const float* cbi, float* hbo, float* cbo,
  float* Xn, int p, int Kx, const int* fl)
{
  if(*fl) enc_cellf_body<1>(Xin,Wih,oWi,Whh,oWh,bih,obi,bhh,obh,hfi,cfi,hfo,cfo,hbi,cbi,hbo,cbo,Xn,p,Kx);
  else    enc_cellf_body<0>(Xin,Wih,oWi,Whh,oWh,bih,obi,bhh,obh,hfi,cfi,hfo,cfo,hbi,cbi,hbo,cbo,Xn,p,Kx);
}

// ---------------------------------------------------------------------------
__global__ void k_decinit(const float* __restrict__ hf, const float* __restrict__ hb,
                          const float* __restrict__ cf, const float* __restrict__ cb,
                          float* __restrict__ dh, float* __restrict__ dc, int l){
  int i = blockIdx.x*256 + threadIdx.x;
  if(i < BH_){
    dh[(size_t)l*BH_ + i] = hf[i] + hb[i];
    dc[(size_t)l*BH_ + i] = cf[i] + cb[i];
  }
}

// ---------------------------------------------------------------------------
// Attention, one block per batch b.
template<int BF> __device__ void attn_body(
  const float* __restrict__ dh, const void* __restrict__ aW,
  const void* __restrict__ av, const float* __restrict__ Epre,
  const float* __restrict__ X3, float* __restrict__ ctx)
{
  __shared__ float z[H_];
  __shared__ float sc[S_];
  int tid = threadIdx.x, b = blockIdx.x;
  int lane = tid & 63, w = tid >> 6;
  const float* htop = dh + (size_t)(2*B_ + b)*H_;
  for(int j = w; j < H_; j += 4){
    size_t wr = (size_t)j*(3*H_);
    float a = 0.f;
    #pragma unroll
    for(int i=0;i<8;i++){
      int k = lane + i*64;
      a = fmaf(htop[k], LD<BF>(aW, wr + k), a);
    }
    a = wred(a);
    if(lane==0) z[j] = a;
  }
  __syncthreads();
  for(int s = w; s < S_; s += 4){
    const float* ep = Epre + (size_t)(s*B_ + b)*H_;
    float a = 0.f;
    #pragma unroll
    for(int i=0;i<8;i++){
      int k = lane + i*64;
      a = fmaf(LD<BF>(av, k), tanhf(ep[k] + z[k]), a);
    }
    a = wred(a);
    if(lane==0) sc[s] = a;
  }
  __syncthreads();
  if(tid < 64){
    float v = sc[tid];
    float m = v;
    #pragma unroll
    for(int off=32; off; off>>=1) m = fmaxf(m, __shfl_down(m, off));
    m = __shfl(m, 0);
    float e = __expf(v - m);
    float sum = e;
    #pragma unroll
    for(int off=32; off; off>>=1) sum += __shfl_down(sum, off);
    sum = __shfl(sum, 0);
    sc[tid] = e / sum;
  }
  __syncthreads();
  for(int d0 = tid; d0 < DIN_; d0 += 256){
    float a = 0.f;
    for(int s=0;s<S_;s++) a = fmaf(sc[s], X3[(size_t)(s*B_ + b)*DIN_ + d0], a);
    ctx[(size_t)b*DIN_ + d0] = a;
  }
}
__global__ __launch_bounds__(256) void k_attn(
  const float* dh, const void* aW, const void* av, const float* Epre,
  const float* X3, float* ctx, const int* fl)
{
  if(*fl) attn_body<1>(dh,aW,av,Epre,X3,ctx);
  else    attn_body<0>(dh,aW,av,Epre,X3,ctx);
}

// ---------------------------------------------------------------------------
// x = [emb[trg[:,t]], ctx] @ proj_W.T + proj_b.  Wave per (b,j).
template<int BF> __device__ void proj_body(
  const int* __restrict__ trg, int t, const void* __restrict__ emb,
  const float* __restrict__ ctx, const void* __restrict__ pW,
  const void* __restrict__ pb, float* __restrict__ xo)
{
  int wave = blockIdx.x*4 + (threadIdx.x>>6);
  int lane = threadIdx.x & 63;
  int j = wave & (DIN_-1);
  int b = wave >> 10;
  int tok = trg[b*S_ + t];
  size_t wr = (size_t)j*(E_ + 2*H_);
  float a = 0.f;
  #pragma unroll
  for(int i=0;i<4;i++){
    int k = lane + i*64;
    a = fmaf(LD<BF>(emb, (size_t)tok*E_ + k), LD<BF>(pW, wr + k), a);
  }
  const float* cr = ctx + (size_t)b*DIN_;
  #pragma unroll
  for(int i=0;i<16;i++){
    int k = lane + i*64;
    a = fmaf(cr[k], LD<BF>(pW, wr + E_ + k), a);
  }
  a = wred(a);
  if(lane==0) xo[(size_t)b*DIN_ + j] = a + LD<BF>(pb, j);
}
__global__ __launch_bounds__(256) void k_proj(
  const int* trg, int t, const void* emb, const float* ctx,
  const void* pW, const void* pb, float* xo, const int* fl)
{
  if(*fl) proj_body<1>(trg,t,emb,ctx,pW,pb,xo);
  else    proj_body<0>(trg,t,emb,ctx,pW,pb,xo);
}

// ---------------------------------------------------------------------------
// Decoder LSTM cell, wave per (b,j).
template<int BF> __device__ void dec_cell_body(
  const float* __restrict__ x, int Kx,
  const void* __restrict__ Wih, size_t oWi,
  const void* __restrict__ Whh, size_t oWh,
  const void* __restrict__ bih, size_t obi,
  const void* __restrict__ bhh, size_t obh,
  const float* __restrict__ h_in, const float* __restrict__ c_in,
  float* __restrict__ h_out, float* __restrict__ c_out)
{
  int wave = blockIdx.x*4 + (threadIdx.x>>6);
  int lane = threadIdx.x & 63;
  int j = wave & (H_-1);
  int b = wave >> 9;
  const float* xr = x + (size_t)b*Kx;
  size_t wi = oWi + (size_t)j*DIN_;
  float a0=0.f,a1=0.f,a2=0.f,a3=0.f;
  for(int k=lane; k<Kx; k+=64){
    float xv = xr[k];
    a0 = fmaf(xv, LD<BF>(Wih, wi + k), a0);
    a1 = fmaf(xv, LD<BF>(Wih, wi + (size_t)H_*DIN_ + k), a1);
    a2 = fmaf(xv, LD<BF>(Wih, wi + (size_t)2*H_*DIN_ + k), a2);
    a3 = fmaf(xv, LD<BF>(Wih, wi + (size_t)3*H_*DIN_ + k), a3);
  }
  size_t wh = oWh + (size_t)j*H_;
  const float* hrow = h_in + b*H_;
  #pragma unroll
  for(int i=0;i<8;i++){
    int k = lane + i*64;
    float hv = hrow[k];
    a0 = fmaf(hv, LD<BF>(Whh, wh + k), a0);
    a1 = fmaf(hv, LD<BF>(Whh, wh + (size_t)H_*H_ + k), a1);
    a2 = fmaf(hv, LD<BF>(Whh, wh + (size_t)2*H_*H_ + k), a2);
    a3 = fmaf(hv, LD<BF>(Whh, wh + (size_t)3*H_*H_ + k), a3);
  }
  a0 = wred(a0); a1 = wred(a1); a2 = wred(a2); a3 = wred(a3);
  if(lane==0){
    float gi = a0 + LD<BF>(bih, obi+j)       + LD<BF>(bhh, obh+j);
    float gf = a1 + LD<BF>(bih, obi+j+H_)    + LD<BF>(bhh, obh+j+H_);
    float gg = a2 + LD<BF>(bih, obi+j+2*H_)  + LD<BF>(bhh, obh+j+2*H_);
    float go = a3 + LD<BF>(bih, obi+j+3*H_)  + LD<BF>(bhh, obh+j+3*H_);
    float c2 = sigm(gf)*c_in[b*H_+j] + sigm(gi)*tanhf(gg);
    float h2 = sigm(go)*tanhf(c2);
    h_out[b*H_+j] = h2;
    c_out[b*H_+j] = c2;
  }
}
__global__ __launch_bounds__(256) void k_dec_cell(
  const float* x, int Kx, const void* Wih, size_t oWi, const void* Whh, size_t oWh,
  const void* bih, size_t obi, const void* bhh, size_t obh,
  const float* hi, const float* ci, float* ho, float* co, const int* fl)
{
  if(*fl) dec_cell_body<1>(x,Kx,Wih,oWi,Whh,oWh,bih,obi,bhh,obh,hi,ci,ho,co);
  else    dec_cell_body<0>(x,Kx,Wih,oWi,Whh,oWh,bih,obi,bhh,obh,hi,ci,ho,co);
}

// ---------------------------------------------------------------------------
// out[b, t+1, v] = h_top @ fc_W[v] + fc_b[v].  Output dtype follows flag:
// flag=1 -> bf16 (u16), flag=0 -> fp32.
template<int BF> __device__ void fc_body(
  const float* __restrict__ dh, const void* __restrict__ fW,
  const void* __restrict__ fb, void* __restrict__ out, int t)
{
  int wave = blockIdx.x*4 + (threadIdx.x>>6);
  int lane = threadIdx.x & 63;
  int v = wave % V_;
  int b = wave / V_;
  const float* hrow = dh + (size_t)(2*B_ + b)*H_;
  float a = 0.f;
  #pragma unroll
  for(int i=0;i<8;i++){
    int k = lane + i*64;
    a = fmaf(hrow[k], LD<BF>(fW, (size_t)v*H_ + k), a);
  }
  a = wred(a);
  if(lane==0){
    float r = a + LD<BF>(fb, v);
    size_t idx = (size_t)b*(S_*V_) + (size_t)(t+1)*V_ + v;
    if constexpr(BF) ((u16*)out)[idx] = f2b(r);
    else             ((float*)out)[idx] = r;
  }
}
__global__ __launch_bounds__(256) void k_fc(
  const float* dh, const void* fW, const void* fb, void* out, int t, const int* fl)
{
  if(*fl) fc_body<1>(dh,fW,fb,out,t);
  else    fc_body<0>(dh,fW,fb,out,t);
}

// out[b,0,:] = 0 in the active output dtype.
__global__ void k_outzero(void* __restrict__ out, const int* fl){
  int i = blockIdx.x*256 + threadIdx.x;
  if(i < B_*V_){
    int b = i / V_, v = i % V_;
    size_t idx = (size_t)b*(S_*V_) + v;
    if(*fl) ((u16*)out)[idx] = 0;
    else    ((float*)out)[idx] = 0.f;
  }
}

// ---------------------------------------------------------------------------
extern "C" void kernel_launch(void* const* d_in, const int* in_sizes, int n_in,
                              void* d_out, int out_size, void* d_ws, size_t ws_size,
                              hipStream_t stream){
  const int* src  = (const int*)d_in[0];
  const int* trg  = (const int*)d_in[1];
  const void* emb = d_in[2];
  const void* eWih= d_in[3];
  const void* eWhh= d_in[4];
  const void* ebih= d_in[5];
  const void* ebhh= d_in[6];
  const void* dWih= d_in[7];
  const void* dWhh= d_in[8];
  const void* dbih= d_in[9];
  const void* dbhh= d_in[10];
  const void* aW  = d_in[11];
  const void* ab  = d_in[12];
  const void* av  = d_in[13];
  const void* pW  = d_in[14];
  const void* pb  = d_in[15];
  const void* fW  = d_in[16];
  const void* fb  = d_in[17];

  char* base = (char*)d_ws;
  size_t off = 0;
  auto take = [&](size_t bytes)->char*{
    char* p = base + off; off = (off + bytes + 255) & ~(size_t)255; return p;
  };

  const size_t szX  = (size_t)2048*1024*4;   // 8 MB
  const size_t szG  = (size_t)2048*4096*4;   // 32 MB
  const size_t szE  = (size_t)2048*512*4;    // 4 MB
  const size_t szSt = (size_t)24*BH_*4;      // 1.5 MB
  int planA = (ws_size >= 2*szX + szG + szE + szSt + 8192);

  float* XA = (float*)take(szX);
  float* XB = (float*)take(szX);
  float* G  = planA ? (float*)take(szG) : nullptr;
  float* Epre = (float*)take(szE);
  float* st   = (float*)take(szSt);
  int* fl     = (int*)take(256);

  float* hf_[2] = { st + 0*BH_, st + 4*BH_ };
  float* cf_[2] = { st + 1*BH_, st + 5*BH_ };
  float* hb_[2] = { st + 2*BH_, st + 6*BH_ };
  float* cb_[2] = { st + 3*BH_, st + 7*BH_ };
  float* dh_[2] = { st + 8*BH_,  st + 11*BH_ };
  float* dc_[2] = { st + 14*BH_, st + 17*BH_ };
  float* ctx = st + 20*BH_;
  float* xp  = ctx + 2*BH_;

  k_detect<<<1, 256, 0, stream>>>(av, fl);
  k_embed<<<8192, 256, 0, stream>>>(src, emb, XA, fl);

  float* Xin = XA; float* Xout = XB;
  for(int l=0;l<L_;l++){
    int K = (l==0) ? E_ : DIN_;
    k_zero<<<256, 256, 0, stream>>>(st, 4*BH_);
    if(planA){
      k_gemm<<<dim3(64,16), 256, 0, stream>>>(Xin, DIN_,
          eWih, DIN_, (size_t)l*2*G4_*DIN_,
          ebih, (size_t)l*2*G4_, ebhh, (size_t)l*2*G4_,
          G, 4096, K, fl);
      for(int p=0;p<S_;p++){
        int c = p & 1, n = c ^ 1;
        k_enc_cell<<<8192, 256, 0, stream>>>(G, eWhh, (size_t)l*2*G4_*H_,
          hf_[c], cf_[c], hf_[n], cf_[n],
          hb_[c], cb_[c], hb_[n], cb_[n], Xout, p, fl);
      }
    } else {
      for(int p=0;p<S_;p++){
        int c = p & 1, n = c ^ 1;
        k_enc_cell_f<<<8192, 256, 0, stream>>>(Xin,
          eWih, (size_t)l*2*G4_*DIN_, eWhh, (size_t)l*2*G4_*H_,
          ebih, (size_t)l*2*G4_, ebhh, (size_t)l*2*G4_,
          hf_[c], cf_[c], hf_[n], cf_[n],
          hb_[c], cb_[c], hb_[n], cb_[n], Xout, p, K, fl);
      }
    }
    k_decinit<<<64, 256, 0, stream>>>(hf_[0], hb_[0], cf_[0], cb_[0],
                                      dh_[0], dc_[0], l);
    float* tmp = Xin; Xin = Xout; Xout = tmp;
  }
  // Epre = enc_out @ attn_W[:,H:].T + attn_b (step-invariant)
  k_gemm<<<dim3(8,16), 256, 0, stream>>>(Xin, DIN_,
      aW, 3*H_, (size_t)H_, ab, 0, nullptr, 0, Epre, H_, DIN_, fl);
  k_outzero<<<12, 256, 0, stream>>>(d_out, fl);

  for(int t=0;t<S_-1;t++){
    int c = t & 1, n = c ^ 1;
    k_attn<<<B_, 256, 0, stream>>>(dh_[c], aW, av, Epre, Xin, ctx, fl);
    k_proj<<<8192, 256, 0, stream>>>(trg, t, emb, ctx, pW, pb, xp, fl);
    for(int l=0;l<L_;l++){
      const float* xl = (l==0) ? xp : (dh_[n] + (size_t)(l-1)*BH_);
      int Kx = (l==0) ? DIN_ : H_;
      k_dec_cell<<<4096, 256, 0, stream>>>(xl, Kx,
        dWih, (size_t)l*G4_*DIN_, dWhh, (size_t)l*G4_*H_,
        dbih, (size_t)l*G4_, dbhh, (size_t)l*G4_,
        dh_[c] + (size_t)l*BH_, dc_[c] + (size_t)l*BH_,
        dh_[n] + (size_t)l*BH_, dc_[n] + (size_t)l*BH_, fl);
    }
    k_fc<<<768, 256, 0, stream>>>(dh_[n], fW, fb, d_out, t, fl);
  }
}